// Round 7
// baseline (744.094 us; speedup 1.0000x reference)
//
#include <hip/hip_runtime.h>
#include <cstdint>
#include <cstddef>

using u16 = unsigned short;
using u32 = unsigned int;

// ---------------- helpers ----------------
__device__ __forceinline__ float bf2f(u16 u){
  union { u32 i; float f; } x; x.i = ((u32)u) << 16; return x.f;
}
__device__ __forceinline__ u16 f2bf(float f){
  union { float f; u32 i; } x; x.f = f;
  u32 r = x.i + 0x7fffu + ((x.i >> 16) & 1u);
  return (u16)(r >> 16);
}
__device__ __forceinline__ float gelu_f(float x){
  return 0.5f * x * (1.0f + erff(x * 0.70710678118654752f));
}
__device__ __forceinline__ void gld16(const void* g, void* l){
  __builtin_amdgcn_global_load_lds((__attribute__((address_space(1))) void*)(void*)g,
                                   (__attribute__((address_space(3))) void*)l, 16, 0, 0);
}

typedef __bf16 bf16x8 __attribute__((ext_vector_type(8)));
typedef float  f32x4  __attribute__((ext_vector_type(4)));

// ---------------- batched weight transpose + cast: 7 matrices fp32 [R,C] -> bf16 [C,R] ----------------
struct TransPack {
  const float* src[7]; u16* dst[7];
  int R[7], C[7], base[8];
};
__global__ __launch_bounds__(256) void k_transpose_all(TransPack p){
  __shared__ u16 tile[32][33];
  int bid = blockIdx.x;
  int m = 0;
#pragma unroll
  for (int i = 1; i < 7; ++i) if (bid >= p.base[i]) m = i;
  int local = bid - p.base[m];
  const float* src = p.src[m]; u16* dst = p.dst[m];
  int R = p.R[m], C = p.C[m];
  int tilesx = C >> 5;
  int bx = (local % tilesx) << 5;
  int by = (local / tilesx) << 5;
  int tx = threadIdx.x & 31;
  int ty = threadIdx.x >> 5;
  for (int r = ty; r < 32; r += 8)
    tile[r][tx] = f2bf(src[(size_t)(by + r) * C + bx + tx]);
  __syncthreads();
  for (int r = ty; r < 32; r += 8)
    dst[(size_t)(bx + r) * R + by + tx] = tile[tx][r];
}

// ---------------- layernorm over last dim (cols = 1024 or 512), optional gelu, bf16 out ----------------
template<bool IN_F32, bool DO_GELU>
__global__ __launch_bounds__(256) void k_layernorm(const void* __restrict__ inp,
    const float* __restrict__ w, const float* __restrict__ bsh,
    u16* __restrict__ out, int cols, float eps){
  int row = blockIdx.x, t = threadIdx.x;
  size_t base = (size_t)row * cols;
  const float* inf = (const float*)inp;
  const u16*  inb = (const u16*)inp;
  float v[4];
  int ep = cols >> 8;
  float s = 0.f, ss = 0.f;
  for (int e = 0; e < ep; ++e){
    int idx = t + (e << 8);
    float x = IN_F32 ? inf[base + idx] : bf2f(inb[base + idx]);
    v[e] = x; s += x; ss += x * x;
  }
#pragma unroll
  for (int off = 1; off < 64; off <<= 1){
    s  += __shfl_xor(s, off, 64);
    ss += __shfl_xor(ss, off, 64);
  }
  __shared__ float red[8];
  int wv = t >> 6;
  if ((t & 63) == 0){ red[wv] = s; red[4 + wv] = ss; }
  __syncthreads();
  s  = red[0] + red[1] + red[2] + red[3];
  ss = red[4] + red[5] + red[6] + red[7];
  float inv = 1.f / (float)cols;
  float mean = s * inv;
  float var = ss * inv - mean * mean;
  float rs = rsqrtf(var + eps);
  for (int e = 0; e < ep; ++e){
    int idx = t + (e << 8);
    float y = (v[e] - mean) * rs * w[idx] + bsh[idx];
    if (DO_GELU) y = gelu_f(y);
    out[base + idx] = f2bf(y);
  }
}

// ---------------- final: out(fp32) = x2(bf16) + LN(c3; ln3) , cols=1024 ----------------
__global__ __launch_bounds__(256) void k_final(const u16* __restrict__ c3,
    const u16* __restrict__ x2, const float* __restrict__ w,
    const float* __restrict__ bsh, float* __restrict__ out){
  int row = blockIdx.x, t = threadIdx.x;
  size_t base = (size_t)row << 10;
  float v[4];
  float s = 0.f, ss = 0.f;
#pragma unroll
  for (int e = 0; e < 4; ++e){
    int idx = t + (e << 8);
    float x = bf2f(c3[base + idx]);
    v[e] = x; s += x; ss += x * x;
  }
#pragma unroll
  for (int off = 1; off < 64; off <<= 1){
    s  += __shfl_xor(s, off, 64);
    ss += __shfl_xor(ss, off, 64);
  }
  __shared__ float red[8];
  int wv = t >> 6;
  if ((t & 63) == 0){ red[wv] = s; red[4 + wv] = ss; }
  __syncthreads();
  s  = red[0] + red[1] + red[2] + red[3];
  ss = red[4] + red[5] + red[6] + red[7];
  float mean = s * (1.f/1024.f);
  float var = ss * (1.f/1024.f) - mean * mean;
  float rs = rsqrtf(var + 1e-6f);
#pragma unroll
  for (int e = 0; e < 4; ++e){
    int idx = t + (e << 8);
    float y = (v[e] - mean) * rs * w[idx] + bsh[idx];
    out[base + idx] = bf2f(x2[base + idx]) + y;
  }
}

// ---------------- MFMA GEMM: C[M,N] = A[M,K](bf16) * Bt[N,K]^T(bf16) (+fp32 bias/res, gelu) ----------------
// m97 structure: 128x128 tile, BK=32, global_load_lds width 16; 3 blocks/CU to overlap barrier drains.
template<bool BIAS, bool GELU, bool RES, bool OUTB, bool OUTF>
__global__ __launch_bounds__(256, 3) void k_gemm(
    const u16* __restrict__ A, const u16* __restrict__ Bt,
    const float* __restrict__ bias, const float* __restrict__ resf,
    u16* __restrict__ outb, float* __restrict__ outf, int N, int K)
{
  __shared__ __align__(16) u16 As[128 * 32];
  __shared__ __align__(16) u16 Bs[128 * 32];
  int t = threadIdx.x, lane = t & 63, wv = t >> 6;
  int m0 = blockIdx.y << 7, n0 = blockIdx.x << 7;
  int wm = (wv >> 1) << 6, wn = (wv & 1) << 6;

  f32x4 acc[4][4];
  const f32x4 z4 = {0.f, 0.f, 0.f, 0.f};
#pragma unroll
  for (int i = 0; i < 4; ++i)
#pragma unroll
    for (int j = 0; j < 4; ++j) acc[i][j] = z4;

  int srow = (wv << 5) + (lane >> 2);
  int skp  = (lane & 3) << 3;
  const u16* Ag = A  + (size_t)(m0 + srow) * K + skp;
  const u16* Bg = Bt + (size_t)(n0 + srow) * K + skp;
  u16* As0 = &As[(wv << 5) * 32];
  u16* As1 = As0 + 16 * 32;
  u16* Bs0 = &Bs[(wv << 5) * 32];
  u16* Bs1 = Bs0 + 16 * 32;
  const size_t rowskip = (size_t)16 * K;

  int fr = lane & 15, fq = (lane >> 4) << 3;

  for (int k0 = 0; k0 < K; k0 += 32){
    gld16(Ag + k0, As0);
    gld16(Ag + rowskip + k0, As1);
    gld16(Bg + k0, Bs0);
    gld16(Bg + rowskip + k0, Bs1);
    __syncthreads();
    bf16x8 af[4], bfr[4];
#pragma unroll
    for (int i = 0; i < 4; ++i)
      af[i] = *(const bf16x8*)&As[(wm + i * 16 + fr) * 32 + fq];
#pragma unroll
    for (int j = 0; j < 4; ++j)
      bfr[j] = *(const bf16x8*)&Bs[(wn + j * 16 + fr) * 32 + fq];
#pragma unroll
    for (int i = 0; i < 4; ++i)
#pragma unroll
      for (int j = 0; j < 4; ++j)
        acc[i][j] = __builtin_amdgcn_mfma_f32_16x16x32_bf16(af[i], bfr[j], acc[i][j], 0, 0, 0);
    __syncthreads();
  }

  int rr = (lane >> 4) << 2;
  int cc = lane & 15;
#pragma unroll
  for (int i = 0; i < 4; ++i)
#pragma unroll
    for (int j = 0; j < 4; ++j){
      int gc = n0 + wn + j * 16 + cc;
      float bb = BIAS ? bias[gc] : 0.f;
#pragma unroll
      for (int r = 0; r < 4; ++r){
        int gr = m0 + wm + i * 16 + rr + r;
        size_t idx = (size_t)gr * N + gc;
        float vv = acc[i][j][r] + bb;
        if (RES) vv += resf[idx];
        if (GELU) vv = gelu_f(vv);
        if (OUTF) outf[idx] = vv;
        if (OUTB) outb[idx] = f2bf(vv);
      }
    }
}

// ---------------- MFMA flash attention v4: transposed-S, b64 p-stores, swizzled K ----------------
// S^T = K*Q^T (operand swap). Q pre-scaled x0.125 (exact), rel pre-scaled x8 (exact) so
// score = S + gh + gw with adds only. Row-sum l via ones column 64 of V^T.
#define ATT_STR 72
__global__ __launch_bounds__(256, 3) void k_attn4(const u16* __restrict__ qkv,
    const float* __restrict__ relh, const float* __restrict__ relw,
    u16* __restrict__ out)
{
  __shared__ __align__(16) u16 k_s[64 * ATT_STR];    // [key][d], chunk-swizzled
  __shared__ __align__(16) u16 vT_s[80 * ATT_STR];   // [d][key]; rows 64..79 ones/zeros
  __shared__ __align__(16) u16 p_s[128 * ATT_STR];   // [q][key]; preamble: rel staging
  __shared__ u16 gh_s[128 * 28];
  __shared__ u16 gw_s[128 * 31];                     // cols 28..30 = wrap pad of 0..2

  const int t = threadIdx.x, lane = t & 63, wv = t >> 6;
  int id = blockIdx.x;
  int xr = id & 7, rest = id >> 3;
  int qt = rest % 7, gg = rest / 7;
  int bnh = xr + (gg << 3);
  const int b = bnh >> 4, nh = bnh & 15;
  const int q0 = qt << 7;
  const size_t rowbase = (size_t)b * 784;
  const int wq0 = wv << 5;
  const int fr = lane & 15;
  const int fq = lane >> 4;

  // ---- preamble: stage rel (x8, bf16) into p_s overlay; init ones rows of vT ----
  u16* rh_s = p_s;
  u16* rw_s = p_s + 64 * ATT_STR;
  {
    int row = t >> 2, c0 = (t & 3) << 4;
    u16 bh_[16], bw_[16];
    if (row < 55){
      const float* ph = relh + row * 64 + c0;
      const float* pw = relw + row * 64 + c0;
#pragma unroll
      for (int e = 0; e < 16; ++e){ bh_[e] = f2bf(ph[e] * 8.f); bw_[e] = f2bf(pw[e] * 8.f); }
    } else {
#pragma unroll
      for (int e = 0; e < 16; ++e){ bh_[e] = 0; bw_[e] = 0; }
    }
    *(uint4*)&rh_s[row * ATT_STR + c0]     = *(uint4*)bh_;
    *(uint4*)&rh_s[row * ATT_STR + c0 + 8] = *(uint4*)(bh_ + 8);
    *(uint4*)&rw_s[row * ATT_STR + c0]     = *(uint4*)bw_;
    *(uint4*)&rw_s[row * ATT_STR + c0 + 8] = *(uint4*)(bw_ + 8);
    for (int idx = t; idx < 16 * ATT_STR; idx += 256){
      int rr = idx / ATT_STR, cc = idx - rr * ATT_STR;
      vT_s[(64 + rr) * ATT_STR + cc] = (rr == 0 && cc < 64) ? (u16)0x3f80 : (u16)0;
    }
  }

  // ---- preload Q B-fragments, pre-scaled by 0.125 (exact pow2) ----
  bf16x8 qf[2][2];
#pragma unroll
  for (int mf = 0; mf < 2; ++mf)
#pragma unroll
    for (int ks = 0; ks < 2; ++ks){
      int row = q0 + wq0 + mf * 16 + fr;
      u16 qs[8];
      if (row < 784){
        const u16* qp = qkv + (rowbase + row) * 3072 + nh * 64 + fq * 8 + ks * 32;
        uint4 q4 = *(const uint4*)qp;
        u16 qe[8]; *(uint4*)qe = q4;
#pragma unroll
        for (int e = 0; e < 8; ++e) qs[e] = f2bf(bf2f(qe[e]) * 0.125f);
      } else {
#pragma unroll
        for (int e = 0; e < 8; ++e) qs[e] = 0;
      }
      qf[mf][ks] = *(bf16x8*)qs;
    }
  __syncthreads();

  const f32x4 z4 = {0.f,0.f,0.f,0.f};
  // ---- bias tables via MFMA: G = (0.125 Q) @ (8 rel)^T = Q @ rel^T; window scatter ----
#pragma unroll
  for (int which = 0; which < 2; ++which){
    const u16* rs = which ? rw_s : rh_s;
    f32x4 G[2][4];
#pragma unroll
    for (int mf = 0; mf < 2; ++mf)
#pragma unroll
      for (int nf = 0; nf < 4; ++nf) G[mf][nf] = z4;
#pragma unroll
    for (int nf = 0; nf < 4; ++nf){
      bf16x8 rf0 = *(const bf16x8*)&rs[(nf * 16 + fr) * ATT_STR + fq * 8];
      bf16x8 rf1 = *(const bf16x8*)&rs[(nf * 16 + fr) * ATT_STR + fq * 8 + 32];
#pragma unroll
      for (int mf = 0; mf < 2; ++mf){
        G[mf][nf] = __builtin_amdgcn_mfma_f32_16x16x32_bf16(qf[mf][0], rf0, G[mf][nf], 0, 0, 0);
        G[mf][nf] = __builtin_amdgcn_mfma_f32_16x16x32_bf16(qf[mf][1], rf1, G[mf][nf], 0, 0, 0);
      }
    }
    u16* gt = which ? gw_s : gh_s;
    int GSTR = which ? 31 : 28;
#pragma unroll
    for (int mf = 0; mf < 2; ++mf)
#pragma unroll
      for (int r = 0; r < 4; ++r){
        int lr = wq0 + mf * 16 + fq * 4 + r;
        int grow = q0 + lr;
        int hq = grow / 28;
        int coord = which ? (grow - hq * 28) : hq;
#pragma unroll
        for (int nf = 0; nf < 4; ++nf){
          int j = nf * 16 + fr;
          int kk = coord + 27 - j;
          if ((unsigned)kk < 28u) gt[lr * GSTR + kk] = f2bf(G[mf][nf][r]);
        }
      }
  }
  __syncthreads();
  // wrap-pad gw cols 28..30
  for (int idx = t; idx < 128 * 3; idx += 256){
    int q = idx / 3, i = idx - q * 3;
    gw_s[q * 31 + 28 + i] = gw_s[q * 31 + i];
  }

  // ---- main K/V loop ----
  f32x4 acc[2][5];
#pragma unroll
  for (int mf = 0; mf < 2; ++mf)
#pragma unroll
    for (int nf = 0; nf < 5; ++nf) acc[mf][nf] = z4;

  for (int kt = 0; kt < 13; ++kt){
    __syncthreads();
    {
      // K staging: thread = one key row, 2 swizzled b128 chunks
      int krow = lane;
      int d0 = wv << 4;
      int jg = (kt << 6) + krow;
      uint4 kv0 = {0u,0u,0u,0u}, kv1 = {0u,0u,0u,0u};
      if (jg < 784){
        const u16* kp = qkv + (rowbase + jg) * 3072 + 1024 + nh * 64 + d0;
        kv0 = *(const uint4*)kp; kv1 = *(const uint4*)(kp + 8);
      }
      int g = (krow >> 3) & 7;
      int c0 = wv << 1;
      *(uint4*)&k_s[krow * ATT_STR + ((c0 ^ g) << 3)]       = kv0;
      *(uint4*)&k_s[krow * ATT_STR + (((c0 + 1) ^ g) << 3)] = kv1;
      // V staging: packed key-pairs, 8 b32 writes
      int j2 = t & 31, dgrp = t >> 5;
      int d0v = dgrp << 3;
      int ja = (kt << 6) + (j2 << 1), jb = ja + 1;
      uint4 va = {0u,0u,0u,0u}, vb = {0u,0u,0u,0u};
      if (ja < 784) va = *(const uint4*)(qkv + (rowbase + ja) * 3072 + 2048 + nh * 64 + d0v);
      if (jb < 784) vb = *(const uint4*)(qkv + (rowbase + jb) * 3072 + 2048 + nh * 64 + d0v);
      u16 va_[8], vb_[8];
      *(uint4*)va_ = va; *(uint4*)vb_ = vb;
#pragma unroll
      for (int e = 0; e < 8; ++e)
        *(u32*)&vT_s[(d0v + e) * ATT_STR + (j2 << 1)] = (u32)va_[e] | ((u32)vb_[e] << 16);
    }
    __syncthreads();

    // QK^T transposed: S^T[key][q] = K (A) x Q (B)
    f32x4 S[4][2];
#pragma unroll
    for (int kf = 0; kf < 4; ++kf){
      int row = kf * 16 + fr;
      int g = (row >> 3) & 7;
      bf16x8 kA0 = *(const bf16x8*)&k_s[row * ATT_STR + ((fq ^ g) << 3)];
      bf16x8 kA1 = *(const bf16x8*)&k_s[row * ATT_STR + (((fq + 4) ^ g) << 3)];
#pragma unroll
      for (int mf = 0; mf < 2; ++mf){
        f32x4 s = z4;
        s = __builtin_amdgcn_mfma_f32_16x16x32_bf16(kA0, qf[mf][0], s, 0, 0, 0);
        s = __builtin_amdgcn_mfma_f32_16x16x32_bf16(kA1, qf[mf][1], s, 0, 0, 0);
        S[kf][mf] = s;
      }
    }

    // bias + exp; pack 4 consecutive keys -> one b64 store
#pragma unroll
    for (int mf = 0; mf < 2; ++mf){
      int qrl = wq0 + mf * 16 + fr;
      const u16* ghrow = &gh_s[qrl * 28];
      const u16* gwrow = &gw_s[qrl * 31];
#pragma unroll
      for (int kf = 0; kf < 4; ++kf){
        int j0 = (kt << 6) + kf * 16 + (fq << 2);
        int j0c = min(j0, 783), j3c = min(j0 + 3, 783);
        int h0 = j0c / 28, h3 = j3c / 28;
        int w0 = j0c - h0 * 28;
        float gh0 = bf2f(ghrow[h0]), gh3 = bf2f(ghrow[h3]);
        float p[4];
#pragma unroll
        for (int r = 0; r < 4; ++r){
          int w = w0 + r;
          float ghv = (w >= 28) ? gh3 : gh0;
          float gwv = bf2f(gwrow[w]);
          float sc = S[kf][mf][r] + ghv + gwv;
          p[r] = (j0 + r < 784) ? __expf(sc) : 0.f;
        }
        u32 lo = (u32)f2bf(p[0]) | ((u32)f2bf(p[1]) << 16);
        u32 hi = (u32)f2bf(p[2]) | ((u32)f2bf(p[3]) << 16);
        uint2 pk; pk.x = lo; pk.y = hi;
        *(uint2*)&p_s[qrl * ATT_STR + kf * 16 + (fq << 2)] = pk;
      }
    }

    // PV (+ ones column -> l); same-wave LDS RAW is in-order, no barrier needed
#pragma unroll
    for (int ks = 0; ks < 2; ++ks){
      bf16x8 pf0 = *(const bf16x8*)&p_s[(wq0 + fr) * ATT_STR + fq * 8 + ks * 32];
      bf16x8 pf1 = *(const bf16x8*)&p_s[(wq0 + 16 + fr) * ATT_STR + fq * 8 + ks * 32];
#pragma unroll
      for (int nf = 0; nf < 5; ++nf){
        bf16x8 vf = *(const bf16x8*)&vT_s[(nf * 16 + fr) * ATT_STR + fq * 8 + ks * 32];
        acc[0][nf] = __builtin_amdgcn_mfma_f32_16x16x32_bf16(pf0, vf, acc[0][nf], 0, 0, 0);
        acc[1][nf] = __builtin_amdgcn_mfma_f32_16x16x32_bf16(pf1, vf, acc[1][nf], 0, 0, 0);
      }
    }
  }

  // epilogue: O[q][d] in C-layout (row=q, col=d); l in col 64 (fr==0 lanes) of acc[.][4]
#pragma unroll
  for (int mf = 0; mf < 2; ++mf){
#pragma unroll
    for (int r = 0; r < 4; ++r){
      float l = __shfl(acc[mf][4][r], lane & 48, 64);
      int row = q0 + wq0 + mf * 16 + fq * 4 + r;
      if (row < 784){
        float inv = 1.f / l;
        u16* dp = out + (rowbase + row) * 1024 + nh * 64 + fr;
#pragma unroll
        for (int nf = 0; nf < 4; ++nf)
          dp[nf * 16] = f2bf(acc[mf][nf][r] * inv);
      }
    }
  }
}

// ---------------- im2col for 3x3 pad-1 conv: g[B,28,28,512](bf16) -> im[6272, 4608] ----------------
__global__ __launch_bounds__(256) void k_im2col(const u16* __restrict__ g, u16* __restrict__ im){
  int idx = blockIdx.x * 256 + threadIdx.x;
  int p  = idx / 576;
  int c8 = idx - p * 576;
  int k0 = c8 << 3;
  int t9 = k0 >> 9;
  int ci = k0 & 511;
  int ky = t9 / 3, kx = t9 - ky * 3;
  int bb = p / 784;
  int s = p - bb * 784;
  int h = s / 28, w = s - h * 28;
  int hh = h + ky - 1, ww = w + kx - 1;
  uint4 val = make_uint4(0u, 0u, 0u, 0u);
  if ((unsigned)hh < 28u && (unsigned)ww < 28u)
    val = *(const uint4*)&g[(((size_t)(bb * 28 + hh)) * 28 + ww) * 512 + ci];
  *(uint4*)&im[(size_t)p * 4608 + k0] = val;
}

// ---------------- orchestration ----------------
extern "C" void kernel_launch(void* const* d_in, const int* in_sizes, int n_in,
                              void* d_out, int out_size, void* d_ws, size_t ws_size,
                              hipStream_t stream)
{
  (void)in_sizes; (void)n_in; (void)out_size; (void)ws_size;
  const float* x      = (const float*)d_in[0];
  const float* n1w    = (const float*)d_in[1];
  const float* n1b    = (const float*)d_in[2];
  const float* qkv_w  = (const float*)d_in[3];
  const float* qkv_b  = (const float*)d_in[4];
  const float* proj_w = (const float*)d_in[5];
  const float* proj_b = (const float*)d_in[6];
  const float* rel_h  = (const float*)d_in[7];
  const float* rel_w  = (const float*)d_in[8];
  const float* n2w    = (const float*)d_in[9];
  const float* n2b    = (const float*)d_in[10];
  const float* fc1_w  = (const float*)d_in[11];
  const float* fc1_b  = (const float*)d_in[12];
  const float* fc2_w  = (const float*)d_in[13];
  const float* fc2_b  = (const float*)d_in[14];
  const float* c1w    = (const float*)d_in[15];
  const float* l1w    = (const float*)d_in[16];
  const float* l1b    = (const float*)d_in[17];
  const float* c2w    = (const float*)d_in[18];
  const float* l2w    = (const float*)d_in[19];
  const float* l2b    = (const float*)d_in[20];
  const float* c3w    = (const float*)d_in[21];
  const float* l3w    = (const float*)d_in[22];
  const float* l3b    = (const float*)d_in[23];

  char* ws = (char*)d_ws;
  size_t off = 0;
  auto alloc = [&](size_t bytes) -> void* {
    void* p = ws + off; off += (bytes + 255) & ~(size_t)255; return p;
  };
  const size_t M = 6272;
  u16* qkvT  = (u16*)alloc((size_t)3072 * 1024 * 2);
  u16* projT = (u16*)alloc((size_t)1024 * 1024 * 2);
  u16* fc1T  = (u16*)alloc((size_t)4096 * 1024 * 2);
  u16* fc2T  = (u16*)alloc((size_t)1024 * 4096 * 2);
  u16* c1T   = (u16*)alloc((size_t)512 * 1024 * 2);
  u16* c2T   = (u16*)alloc((size_t)512 * 4608 * 2);
  u16* c3T   = (u16*)alloc((size_t)1024 * 512 * 2);
  u16* qkvbuf = (u16*)alloc(M * 3072 * 2);
  u16* attn   = (u16*)alloc(M * 1024 * 2);
  u16* xn     = (u16*)alloc(M * 1024 * 2);
  float* x1   = (float*)alloc(M * 1024 * 4);
  u16* x2b    = (u16*)alloc(M * 1024 * 2);
  u16* c1buf  = (u16*)alloc(M * 512 * 2);
  u16* g1buf  = (u16*)alloc(M * 512 * 2);
  u16* hmlp   = qkvbuf;
  u16* im     = qkvbuf;
  u16* xn2    = xn;
  u16* c2buf  = c1buf;
  u16* g2buf  = g1buf;
  u16* c3buf  = attn;

  dim3 blk(256);
  // batched weight transposes+casts (one launch)
  {
    TransPack tp;
    const float* srcs[7] = {qkv_w, proj_w, fc1_w, fc2_w, c1w, c2w, c3w};
    u16* dsts[7] = {qkvT, projT, fc1T, fc2T, c1T, c2T, c3T};
    int Rs[7] = {1024, 1024, 1024, 4096, 1024, 4608, 512};
    int Cs[7] = {3072, 1024, 4096, 1024, 512, 512, 1024};
    int base = 0;
    for (int i = 0; i < 7; ++i){
      tp.src[i] = srcs[i]; tp.dst[i] = dsts[i]; tp.R[i] = Rs[i]; tp.C[i] = Cs[i];
      tp.base[i] = base;
      base += (Rs[i] >> 5) * (Cs[i] >> 5);
    }
    tp.base[7] = base;
    k_transpose_all<<<base, blk, 0, stream>>>(tp);
  }

  k_layernorm<true,false><<<6272, blk, 0, stream>>>(x, n1w, n1b, xn, 1024, 1e-5f);
  k_gemm<true,false,false,true,false><<<dim3(24,49), blk, 0, stream>>>(
      xn, qkvT, qkv_b, nullptr, qkvbuf, nullptr, 3072, 1024);
  k_attn4<<<896, blk, 0, stream>>>(qkvbuf, rel_h, rel_w, attn);
  k_gemm<true,false,true,false,true><<<dim3(8,49), blk, 0, stream>>>(
      attn, projT, proj_b, x, nullptr, x1, 1024, 1024);
  k_layernorm<true,false><<<6272, blk, 0, stream>>>(x1, n2w, n2b, xn2, 1024, 1e-5f);
  k_gemm<true,true,false,true,false><<<dim3(32,49), blk, 0, stream>>>(
      xn2, fc1T, fc1_b, nullptr, hmlp, nullptr, 4096, 1024);
  k_gemm<true,false,true,true,false><<<dim3(8,49), blk, 0, stream>>>(
      hmlp, fc2T, fc2_b, x1, x2b, nullptr, 1024, 4096);
  k_gemm<false,false,false,true,false><<<dim3(4,49), blk, 0, stream>>>(
      x2b, c1T, nullptr, nullptr, c1buf, nullptr, 512, 1024);
  k_layernorm<false,true><<<6272, blk, 0, stream>>>(c1buf, l1w, l1b, g1buf, 512, 1e-6f);
  k_im2col<<<14112, blk, 0, stream>>>(g1buf, im);
  k_gemm<false,false,false,true,false><<<dim3(4,49), blk, 0, stream>>>(
      im, c2T, nullptr, nullptr, c2buf, nullptr, 512, 4608);
  k_layernorm<false,true><<<6272, blk, 0, stream>>>(c2buf, l2w, l2b, g2buf, 512, 1e-6f);
  k_gemm<false,false,false,true,false><<<dim3(8,49), blk, 0, stream>>>(
      g2buf, c3T, nullptr, nullptr, c3buf, nullptr, 1024, 512);
  k_final<<<6272, blk, 0, stream>>>(c3buf, x2b, l3w, l3b, (float*)d_out);
}